// Round 2
// baseline (285.570 us; speedup 1.0000x reference)
//
#include <hip/hip_runtime.h>
#include <stdint.h>

// GCN 2-layer: 256 -> 3 (relu) -> 1, N=131072, E=4194304.
// Round 10 = round 9 with the LDS overflow fixed: lbuf was 256x64x4 = 64 KB
// + lcnt/lbase 2 KB > the 64 KB static __shared__ cap -> build failure.
// LCAP 64 -> 56 (59.3 KB total; mean fill 32/tile, +4.2 sigma; overflow takes
// the direct-global-atomic fallback). Everything else as round 9:
// 256 dst-buckets of 512 nodes (dst>>9, packed u32 = src<<9 | dst&511).
// One block per bucket fully owns its 512-node range in LDS, so ALL
// cross-block staging dies: scatter1 fuses the rlin2 epilogue (h2q written
// directly), scatter2 fuses the output epilogue (only the 64 output-eligible
// buckets, B%8<2, are read -> 4.2 MB not 16.8), degree hist fuses dinv+con
// packing. Bucket & gemv merge into one kernel via block-range split.
// Bucket cursors padded to 64 B apart. 9 kernels -> 5.
// Scratch: xbuf only, 256 buckets x 32768 slots x 4 B = 32 MiB.
// Meta ws (17N + 16.5 KB): deg8 | dinv | h1con | h2q | flag | gcur(padded).
// Quantization identical to round 8: layer1 con = 3x21-bit biased fields in
// u64 (q=1/512, bias 8192, exact de-bias via deg8); layer2 h2 i32 q=2^-14.
#define F_IN 256
#define QSCALE 512.0f
#define QBIAS  8192
#define FMASK  0x1FFFFFull
#define H2Q    16384.0f
#define NBUK   256
#define BSH    9
#define BMASK  511u
#define BCAP   32768           // slots per bucket (128 KB each; mean fill 16384)
#define BCSH   15              // log2(BCAP)
#define LCAP   56              // per-tile LDS bucket capacity (mean 32 + 4.2 sigma)
#define EPB    8192            // edges per bucket block (1024 thr x 8)
#define XBUF_SZ ((size_t)NBUK * BCAP * 4)   // 32 MiB

__device__ __forceinline__ float bf2f(unsigned short u) {
    union { unsigned int i; float f; } v; v.i = ((unsigned int)u) << 16; return v.f;
}
__device__ __forceinline__ unsigned short f2bf(float f) {
    union { unsigned int i; float f; } v; v.f = f;
    unsigned int r = v.i + 0x7FFF + ((v.i >> 16) & 1);
    return (unsigned short)(r >> 16);
}
__device__ __forceinline__ unsigned long long packq(float v0, float v1, float v2) {
    int m0 = __float2int_rn(v0 * QSCALE);
    int m1 = __float2int_rn(v1 * QSCALE);
    int m2 = __float2int_rn(v2 * QSCALE);
    m0 = max(-4095, min(4095, m0));
    m1 = max(-4095, min(4095, m1));
    m2 = max(-4095, min(4095, m2));
    return (unsigned long long)(unsigned)(m0 + QBIAS)
         | ((unsigned long long)(unsigned)(m1 + QBIAS) << 21)
         | ((unsigned long long)(unsigned)(m2 + QBIAS) << 42);
}

// One block: zero padded bucket cursors + detect dtype from W1's first 384 words.
__global__ void k_init(unsigned int* __restrict__ gcur,
                       const unsigned int* __restrict__ w1w, int* __restrict__ flag) {
    __shared__ int cnt;
    if (threadIdx.x == 0) cnt = 0;
    for (int i = threadIdx.x; i < NBUK * 16; i += blockDim.x) gcur[i] = 0u;
    __syncthreads();
    int local = 0;
    for (int i = threadIdx.x; i < 384; i += blockDim.x) {
        unsigned e = (w1w[i] >> 7) & 0xFF;
        if (e >= 100 && e <= 135) local++;
    }
    atomicAdd(&cnt, local);
    __syncthreads();
    if (threadIdx.x == 0) *flag = (2 * cnt < 384) ? 1 : 0;
}

// Fused: blocks [0,bucketB) bucket edges by dst>>9 into xbuf; blocks
// [bucketB, bucketB+gemvB) do gemv1 (16 waves x 2 rows, bf16 h1 out).
// Independent memory streams overlap in one launch.
__global__ void __launch_bounds__(1024)
k_bucket_gemv(int bucketB,
              const int* __restrict__ src, const int* __restrict__ dst,
              unsigned int* __restrict__ xbuf, unsigned int* __restrict__ gcur,
              const void* __restrict__ xv_, const void* __restrict__ w1_,
              unsigned short* __restrict__ h1out,
              const int* __restrict__ flag, int N) {
    __shared__ unsigned int lbuf[NBUK][LCAP];   // 56 KB (static cap is 64 KB!)
    __shared__ unsigned int lcnt[NBUK];
    __shared__ unsigned int lbase[NBUK];
    int b = blockIdx.x;
    if (b < bucketB) {
        for (int i = threadIdx.x; i < NBUK; i += 1024) lcnt[i] = 0u;
        __syncthreads();
        int g4 = b * 2048 + threadIdx.x;        // int4 index; block covers 8192 edges
        int4 sa = ((const int4*)src)[g4];
        int4 da = ((const int4*)dst)[g4];
        int4 sb = ((const int4*)src)[g4 + 1024];
        int4 db = ((const int4*)dst)[g4 + 1024];
        int ss[8] = {sa.x, sa.y, sa.z, sa.w, sb.x, sb.y, sb.z, sb.w};
        int dd[8] = {da.x, da.y, da.z, da.w, db.x, db.y, db.z, db.w};
        #pragma unroll
        for (int u = 0; u < 8; u++) {
            unsigned p = ((unsigned)ss[u] << BSH) | ((unsigned)dd[u] & BMASK);
            int bk = ((unsigned)dd[u]) >> BSH;
            unsigned lp = atomicAdd(&lcnt[bk], 1u);
            if (lp < LCAP) lbuf[bk][lp] = p;
            else {                               // rare (+4.2 sigma tail)
                unsigned g = atomicAdd(&gcur[bk << 4], 1u);
                if (g < BCAP) xbuf[((size_t)bk << BCSH) + g] = p;
            }
        }
        __syncthreads();
        if (threadIdx.x < NBUK) {
            unsigned c = min(lcnt[threadIdx.x], (unsigned)LCAP);
            lcnt[threadIdx.x] = c;
            lbase[threadIdx.x] = atomicAdd(&gcur[threadIdx.x << 4], c);
        }
        __syncthreads();
        int wave = threadIdx.x >> 6, lane = threadIdx.x & 63;
        for (int bk = wave * 16; bk < wave * 16 + 16; bk++) {   // 16 buckets/wave
            unsigned c = lcnt[bk], base = lbase[bk];
            for (unsigned i = lane; i < c; i += 64)
                xbuf[((size_t)bk << BCSH) + base + i] = lbuf[bk][i];
        }
        return;
    }
    // gemv path: 2 rows per wave
    int wave = threadIdx.x >> 6;
    int lane = threadIdx.x & 63;
    int row0 = ((b - bucketB) * 16 + wave) * 2;
    if (row0 >= N) return;
    int f32mode = *flag;

    float xa0, xa1, xa2, xa3, xb0, xb1, xb2, xb3;
    float w00, w01, w02, w10, w11, w12, w20, w21, w22, w30, w31, w32; // w[c][j]
    if (f32mode) {
        const float4* xra = (const float4*)((const float*)xv_ + (size_t)row0 * F_IN);
        const float4* xrb = (const float4*)((const float*)xv_ + (size_t)(row0 + 1) * F_IN);
        float4 va = xra[lane], vb = xrb[lane];
        xa0 = va.x; xa1 = va.y; xa2 = va.z; xa3 = va.w;
        xb0 = vb.x; xb1 = vb.y; xb2 = vb.z; xb3 = vb.w;
        const float4* wr = (const float4*)w1_;
        float4 wa = wr[lane*3+0], wb = wr[lane*3+1], wc = wr[lane*3+2];
        w00 = wa.x; w01 = wa.y; w02 = wa.z; w10 = wa.w;
        w11 = wb.x; w12 = wb.y; w20 = wb.z; w21 = wb.w;
        w22 = wc.x; w30 = wc.y; w31 = wc.z; w32 = wc.w;
    } else {
        const ushort4* xra = (const ushort4*)((const unsigned short*)xv_ + (size_t)row0 * F_IN);
        const ushort4* xrb = (const ushort4*)((const unsigned short*)xv_ + (size_t)(row0 + 1) * F_IN);
        ushort4 va = xra[lane], vb = xrb[lane];
        xa0 = bf2f(va.x); xa1 = bf2f(va.y); xa2 = bf2f(va.z); xa3 = bf2f(va.w);
        xb0 = bf2f(vb.x); xb1 = bf2f(vb.y); xb2 = bf2f(vb.z); xb3 = bf2f(vb.w);
        const ushort4* wr = (const ushort4*)w1_;
        ushort4 wa = wr[lane*3+0], wb = wr[lane*3+1], wc = wr[lane*3+2];
        w00 = bf2f(wa.x); w01 = bf2f(wa.y); w02 = bf2f(wa.z); w10 = bf2f(wa.w);
        w11 = bf2f(wb.x); w12 = bf2f(wb.y); w20 = bf2f(wb.z); w21 = bf2f(wb.w);
        w22 = bf2f(wc.x); w30 = bf2f(wc.y); w31 = bf2f(wc.z); w32 = bf2f(wc.w);
    }
    float pa0 = xa0*w00 + xa1*w10 + xa2*w20 + xa3*w30;
    float pa1 = xa0*w01 + xa1*w11 + xa2*w21 + xa3*w31;
    float pa2 = xa0*w02 + xa1*w12 + xa2*w22 + xa3*w32;
    float pb0 = xb0*w00 + xb1*w10 + xb2*w20 + xb3*w30;
    float pb1 = xb0*w01 + xb1*w11 + xb2*w21 + xb3*w31;
    float pb2 = xb0*w02 + xb1*w12 + xb2*w22 + xb3*w32;
    #pragma unroll
    for (int off = 32; off; off >>= 1) {
        pa0 += __shfl_down(pa0, off, 64);
        pa1 += __shfl_down(pa1, off, 64);
        pa2 += __shfl_down(pa2, off, 64);
        pb0 += __shfl_down(pb0, off, 64);
        pb1 += __shfl_down(pb1, off, 64);
        pb2 += __shfl_down(pb2, off, 64);
    }
    if (lane == 0) {
        ushort4 oa, ob;
        oa.x = f2bf(pa0); oa.y = f2bf(pa1); oa.z = f2bf(pa2); oa.w = 0;
        ob.x = f2bf(pb0); ob.y = f2bf(pb1); ob.z = f2bf(pb2); ob.w = 0;
        ((ushort4*)h1out)[row0]     = oa;
        ((ushort4*)h1out)[row0 + 1] = ob;
    }
}

// One block per bucket: degree hist of its 512 nodes from its own edge list,
// then deg8/dinv write + in-place h1(bf16x4) -> con(u64) pack. No staging.
__global__ void __launch_bounds__(1024)
k_hist_pack(const unsigned int* __restrict__ xbuf, const unsigned int* __restrict__ gcur,
            unsigned char* __restrict__ deg8, float* __restrict__ dinv,
            unsigned long long* __restrict__ h1con) {
    __shared__ unsigned int cnt[512];
    int B = blockIdx.x;
    for (int i = threadIdx.x; i < 512; i += 1024) cnt[i] = 0u;
    __syncthreads();
    unsigned ce = min(gcur[B << 4], (unsigned)BCAP);
    const unsigned int* bp = xbuf + ((size_t)B << BCSH);
    for (unsigned i = threadIdx.x; i < ce; i += 1024)
        atomicAdd(&cnt[bp[i] & BMASK], 1u);
    __syncthreads();
    if (threadIdx.x < 512) {
        int n = (B << BSH) | threadIdx.x;
        unsigned deg = 1u + cnt[threadIdx.x];            // self-loop
        deg8[n] = (unsigned char)min(deg, 255u);
        float dv = rsqrtf((float)deg);
        dinv[n] = dv;
        ushort4 h = ((const ushort4*)h1con)[n];
        h1con[n] = packq(bf2f(h.x) * dv, bf2f(h.y) * dv, bf2f(h.z) * dv);
    }
}

// One block per bucket: LDS u64 accumulate over its 512 nodes, then fused
// epilogue (exact de-bias, *dinv, +b1, relu, W2, *dinv, i32 quantize) -> h2q.
__global__ void __launch_bounds__(1024)
k_scat1_lin2(const unsigned int* __restrict__ xbuf, const unsigned int* __restrict__ gcur,
             const unsigned long long* __restrict__ con,
             const unsigned char* __restrict__ deg8, const float* __restrict__ dinv,
             const void* __restrict__ b1_, const void* __restrict__ w2_,
             int* __restrict__ h2q, const int* __restrict__ flag) {
    __shared__ unsigned long long acc[512];              // 4 KB
    int B = blockIdx.x;
    for (int i = threadIdx.x; i < 512; i += 1024) acc[i] = 0ull;
    __syncthreads();
    unsigned ce = min(gcur[B << 4], (unsigned)BCAP);
    const unsigned int* bp = xbuf + ((size_t)B << BCSH);
    for (unsigned i = threadIdx.x; i < ce; i += 1024) {
        unsigned p = bp[i];
        atomicAdd(&acc[p & BMASK], con[p >> BSH]);
    }
    __syncthreads();
    if (threadIdx.x < 512) {
        int n = (B << BSH) | threadIdx.x;
        int f32mode = *flag;
        float b10, b11, b12, w20, w21, w22;
        if (f32mode) {
            const float* b1 = (const float*)b1_; const float* w2 = (const float*)w2_;
            b10 = b1[0]; b11 = b1[1]; b12 = b1[2];
            w20 = w2[0]; w21 = w2[1]; w22 = w2[2];
        } else {
            const unsigned short* b1 = (const unsigned short*)b1_;
            const unsigned short* w2 = (const unsigned short*)w2_;
            b10 = bf2f(b1[0]); b11 = bf2f(b1[1]); b12 = bf2f(b1[2]);
            w20 = bf2f(w2[0]); w21 = bf2f(w2[1]); w22 = bf2f(w2[2]);
        }
        unsigned long long T = acc[threadIdx.x] + con[n];    // + self-loop
        long long dbias = (long long)deg8[n] * QBIAS;
        float q = 1.0f / QSCALE;
        float s0 = (float)((long long)( T        & FMASK) - dbias) * q;
        float s1 = (float)((long long)((T >> 21) & FMASK) - dbias) * q;
        float s2 = (float)((long long)((T >> 42) & FMASK) - dbias) * q;
        float dv = dinv[n];
        float a0 = fmaxf(s0 * dv + b10, 0.0f);
        float a1 = fmaxf(s1 * dv + b11, 0.0f);
        float a2 = fmaxf(s2 * dv + b12, 0.0f);
        float h2 = (a0 * w20 + a1 * w21 + a2 * w22) * dv;
        h2q[n] = __float2int_rn(h2 * H2Q);
    }
}

// Layer-2 scatter + output epilogue. Output nodes satisfy (n&4095)<1024, i.e.
// whole buckets with B%8 in {0,1}: only those 64 buckets are read at all.
__global__ void __launch_bounds__(1024)
k_scat2_out(const unsigned int* __restrict__ xbuf, const unsigned int* __restrict__ gcur,
            const int* __restrict__ h2q, const float* __restrict__ dinv,
            const void* __restrict__ b2_, void* __restrict__ out_,
            const int* __restrict__ flag) {
    __shared__ int acc[512];
    int ob = blockIdx.x;                                 // 0..63
    int B = ((ob >> 1) << 3) | (ob & 1);                 // buckets with B%8 < 2
    for (int i = threadIdx.x; i < 512; i += 1024) acc[i] = 0;
    __syncthreads();
    unsigned ce = min(gcur[B << 4], (unsigned)BCAP);
    const unsigned int* bp = xbuf + ((size_t)B << BCSH);
    for (unsigned i = threadIdx.x; i < ce; i += 1024) {
        unsigned p = bp[i];
        atomicAdd(&acc[p & BMASK], h2q[p >> BSH]);
    }
    __syncthreads();
    if (threadIdx.x < 512) {
        int i = threadIdx.x;
        int n = (B << BSH) | i;
        int f32mode = *flag;
        float b2 = f32mode ? ((const float*)b2_)[0] : bf2f(((const unsigned short*)b2_)[0]);
        int S = h2q[n] + acc[i];                         // + self-loop
        float v = (float)S * (1.0f / H2Q) * dinv[n] + b2;
        int t = ((B >> 3) << 10) | ((B & 1) << 9) | i;   // batch<<10 | pos
        if (f32mode) ((float*)out_)[t] = v;
        else         ((unsigned short*)out_)[t] = f2bf(v);
    }
}

extern "C" void kernel_launch(void* const* d_in, const int* in_sizes, int n_in,
                              void* d_out, int out_size, void* d_ws, size_t ws_size,
                              hipStream_t stream) {
    void*       x   = d_in[0];              // dead after gemv in fallback mode
    const void* w1  = d_in[1];
    const void* b1  = d_in[2];
    const void* w2  = d_in[3];
    const void* b2  = d_in[4];
    const int* eidx = (const int*)d_in[5];

    const int N = in_sizes[0] / F_IN;       // 131072
    const int E = in_sizes[5] / 2;          // 4194304
    const int* src = eidx;
    const int* dst = eidx + E;

    char* ws = (char*)d_ws;
    unsigned char*      deg8  = (unsigned char*)(ws);
    float*              dinv  = (float*)(ws + (size_t)N);
    unsigned long long* h1con = (unsigned long long*)(ws + (size_t)5*N);
    int*                h2q   = (int*)(ws + (size_t)13*N);
    int*                flag  = (int*)(ws + (size_t)17*N);
    unsigned int*       gcur  = (unsigned int*)(ws + (size_t)17*N + 64); // 16 KB padded

    // xbuf (32 MiB) in d_ws if big enough (measured 512 MiB); else reuse the
    // dead x input buffer (>= 64 MiB), gemv ordered before bucket.
    bool big_ws = ws_size >= ((size_t)(4u << 20) + XBUF_SZ);
    unsigned int* xbuf = (unsigned int*)(big_ws ? (ws + (4u << 20)) : (char*)x);

    int bucketB = E / EPB;                  // 512
    int gemvB   = N / 32;                   // 4096: 16 waves x 2 rows per block
    k_init<<<1, 256, 0, stream>>>(gcur, (const unsigned int*)w1, flag);
    if (big_ws) {
        k_bucket_gemv<<<bucketB + gemvB, 1024, 0, stream>>>(bucketB, src, dst,
                                                            xbuf, gcur, x, w1,
                                                            (unsigned short*)h1con,
                                                            flag, N);
    } else {
        // gemv must consume x before bucket overwrites it
        k_bucket_gemv<<<gemvB, 1024, 0, stream>>>(0, src, dst, xbuf, gcur,
                                                  x, w1, (unsigned short*)h1con,
                                                  flag, N);
        k_bucket_gemv<<<bucketB, 1024, 0, stream>>>(bucketB, src, dst, xbuf, gcur,
                                                    x, w1, (unsigned short*)h1con,
                                                    flag, N);
    }
    k_hist_pack  <<<NBUK, 1024, 0, stream>>>(xbuf, gcur, deg8, dinv, h1con);
    k_scat1_lin2 <<<NBUK, 1024, 0, stream>>>(xbuf, gcur, h1con, deg8, dinv,
                                             b1, w2, h2q, flag);
    k_scat2_out  <<<64, 1024, 0, stream>>>(xbuf, gcur, h2q, dinv, b2, d_out, flag);
}